// Round 6
// baseline (689.339 us; speedup 1.0000x reference)
//
#include <hip/hip_runtime.h>
#include <hip/hip_bf16.h>

// Problem constants (HeteroGATLayer): H=4 heads, D=16, IN=64, E=400000, N=100000
constexpr int IN_F = 64;   // input feature dim
constexpr int HD   = 64;   // H*D
constexpr int BN   = 128;  // nodes per projection block (2 per thread)

// binned counting-sort parameters
constexpr int BW_BITS = 10;
constexpr int BWIDTH  = 1 << BW_BITS;   // 1024 dst nodes per bucket
constexpr int BCAP    = 6144;           // max edges per bucket (avg 4096, sigma~64)
constexpr int BIN_EPT = 16;             // edges per thread in bin pass
constexpr int BIN_CHUNK = 256 * BIN_EPT; // 4096 edges per block

static __device__ __forceinline__ float bf2f(unsigned short u) {
  union { unsigned int i; float f; } c; c.i = ((unsigned int)u) << 16; return c.f;
}
static __device__ __forceinline__ unsigned short f2bf_bits(float f) {
  union { __hip_bfloat16 h; unsigned short u; } c; c.h = __float2bfloat16(f); return c.u;
}

// ---------------------------------------------------------------------------
// Projection kernel: for each node type t (blockIdx.y), 2 nodes per thread:
//   proj 0: h_self = feat@W_t + b_t  -> ddot_r[n,h] for the 3 rels with dst==t
//   proj 1..3: Wh_r = feat@W_r + b_r -> store bf16 Wh_r row + sdot_r[n,h]
// ---------------------------------------------------------------------------
struct ProjParams {
  const float* feat[3];
  const float* Wp[3][4];
  const float* bp[3][4];
  const float* adst[9];
  const float* asrc[9];
  __hip_bfloat16* wh[9];     // out: [N, 64] bf16
  float* sdot[9];            // out: [N, 4]
  float* ddot[9];            // out: [N, 4]
  int N;
};

__global__ __launch_bounds__(256) void proj_kernel(ProjParams p) {
  const int t  = blockIdx.y;
  const int n0 = blockIdx.x * BN;
  const int tid = threadIdx.x;
  const int N = p.N;

  __shared__ float featL[BN][IN_F + 1];   // 33.3 KB
  __shared__ float WL[IN_F][HD];          // 16 KB

  {
    const float* feat = p.feat[t];
    for (int i = tid; i < BN * (IN_F / 4); i += 256) {
      const int row = i >> 4;
      const int c4  = (i & 15) << 2;
      float4 v = make_float4(0.f, 0.f, 0.f, 0.f);
      const int n = n0 + row;
      if (n < N) v = *(const float4*)(feat + (size_t)n * IN_F + c4);
      featL[row][c4 + 0] = v.x; featL[row][c4 + 1] = v.y;
      featL[row][c4 + 2] = v.z; featL[row][c4 + 3] = v.w;
    }
  }

  const int node = tid >> 2;      // 0..63
  const int cg   = tid & 3;       // head index (16 cols per head)
  const int cg16 = cg * 16;
  const int nA   = n0 + node;
  const int nB   = n0 + node + 64;

  for (int pr = 0; pr < 4; ++pr) {
    __syncthreads();
    {
      const float* W = p.Wp[t][pr];
      for (int i = tid; i < IN_F * HD / 4; i += 256) {
        *(float4*)(&WL[0][0] + i * 4) = *(const float4*)(W + i * 4);
      }
    }
    __syncthreads();

    const float* b = p.bp[t][pr];
    float acc0[16], acc1[16];
    #pragma unroll
    for (int jj = 0; jj < 16; ++jj) { acc0[jj] = b[cg16 + jj]; acc1[jj] = acc0[jj]; }

    #pragma unroll 4
    for (int k = 0; k < IN_F; ++k) {
      const float a0 = featL[node][k];
      const float a1 = featL[node + 64][k];
      const float4 w0 = *(const float4*)(&WL[k][cg16 + 0]);
      const float4 w1 = *(const float4*)(&WL[k][cg16 + 4]);
      const float4 w2 = *(const float4*)(&WL[k][cg16 + 8]);
      const float4 w3 = *(const float4*)(&WL[k][cg16 + 12]);
      acc0[0]  = fmaf(a0, w0.x, acc0[0]);  acc0[1]  = fmaf(a0, w0.y, acc0[1]);
      acc0[2]  = fmaf(a0, w0.z, acc0[2]);  acc0[3]  = fmaf(a0, w0.w, acc0[3]);
      acc0[4]  = fmaf(a0, w1.x, acc0[4]);  acc0[5]  = fmaf(a0, w1.y, acc0[5]);
      acc0[6]  = fmaf(a0, w1.z, acc0[6]);  acc0[7]  = fmaf(a0, w1.w, acc0[7]);
      acc0[8]  = fmaf(a0, w2.x, acc0[8]);  acc0[9]  = fmaf(a0, w2.y, acc0[9]);
      acc0[10] = fmaf(a0, w2.z, acc0[10]); acc0[11] = fmaf(a0, w2.w, acc0[11]);
      acc0[12] = fmaf(a0, w3.x, acc0[12]); acc0[13] = fmaf(a0, w3.y, acc0[13]);
      acc0[14] = fmaf(a0, w3.z, acc0[14]); acc0[15] = fmaf(a0, w3.w, acc0[15]);
      acc1[0]  = fmaf(a1, w0.x, acc1[0]);  acc1[1]  = fmaf(a1, w0.y, acc1[1]);
      acc1[2]  = fmaf(a1, w0.z, acc1[2]);  acc1[3]  = fmaf(a1, w0.w, acc1[3]);
      acc1[4]  = fmaf(a1, w1.x, acc1[4]);  acc1[5]  = fmaf(a1, w1.y, acc1[5]);
      acc1[6]  = fmaf(a1, w1.z, acc1[6]);  acc1[7]  = fmaf(a1, w1.w, acc1[7]);
      acc1[8]  = fmaf(a1, w2.x, acc1[8]);  acc1[9]  = fmaf(a1, w2.y, acc1[9]);
      acc1[10] = fmaf(a1, w2.z, acc1[10]); acc1[11] = fmaf(a1, w2.w, acc1[11]);
      acc1[12] = fmaf(a1, w3.x, acc1[12]); acc1[13] = fmaf(a1, w3.y, acc1[13]);
      acc1[14] = fmaf(a1, w3.z, acc1[14]); acc1[15] = fmaf(a1, w3.w, acc1[15]);
    }

    if (pr == 0) {
      #pragma unroll
      for (int sj = 0; sj < 3; ++sj) {
        const int ri = sj * 3 + t;
        const float* ad = p.adst[ri] + cg16;
        float s0 = 0.f, s1 = 0.f;
        #pragma unroll
        for (int jj = 0; jj < 16; ++jj) {
          const float av = ad[jj];
          s0 = fmaf(acc0[jj], av, s0);
          s1 = fmaf(acc1[jj], av, s1);
        }
        if (nA < N) p.ddot[ri][(size_t)nA * 4 + cg] = s0;
        if (nB < N) p.ddot[ri][(size_t)nB * 4 + cg] = s1;
      }
    } else {
      const int ri = t * 3 + (pr - 1);
      const float* as = p.asrc[ri] + cg16;
      float s0 = 0.f, s1 = 0.f;
      #pragma unroll
      for (int jj = 0; jj < 16; ++jj) {
        const float av = as[jj];
        s0 = fmaf(acc0[jj], av, s0);
        s1 = fmaf(acc1[jj], av, s1);
      }
      if (nA < N) {
        __hip_bfloat16* whp = p.wh[ri] + (size_t)nA * HD + cg16;
        #pragma unroll
        for (int jj = 0; jj < 16; ++jj) whp[jj] = __float2bfloat16(acc0[jj]);
        p.sdot[ri][(size_t)nA * 4 + cg] = s0;
      }
      if (nB < N) {
        __hip_bfloat16* whp = p.wh[ri] + (size_t)nB * HD + cg16;
        #pragma unroll
        for (int jj = 0; jj < 16; ++jj) whp[jj] = __float2bfloat16(acc1[jj]);
        p.sdot[ri][(size_t)nB * 4 + cg] = s1;
      }
    }
  }
}

// ---------------------------------------------------------------------------
// CSR build, two-pass binned counting sort. Pass B also computes per-edge
// alpha (softmax over heads) once, written coalesced.
// ---------------------------------------------------------------------------
struct EdgeLists { const int* src[9]; const int* dst[9]; int E; int N; };

__global__ __launch_bounds__(256) void zero_u32_kernel(unsigned* p, int n) {
  const int i = blockIdx.x * 256 + threadIdx.x;
  if (i < n) p[i] = 0u;
}

// Pass A: bin edges into buckets of BWIDTH dst nodes; packed u32 per edge:
//   src (17 bits) | dstLow (10 bits) << 17
__global__ __launch_bounds__(256) void bin_kernel(EdgeLists el, unsigned* bcnt,
                                                  unsigned* binBuf, int nbuck) {
  const int r   = blockIdx.y;
  const int tid = threadIdx.x;
  const int e0  = blockIdx.x * BIN_CHUNK;
  const int E   = el.E;
  const int* srcp = el.src[r];
  const int* dstp = el.dst[r];

  __shared__ unsigned bh[128], bcur[128], bbase[128];
  if (tid < 128) { bh[tid] = 0u; bcur[tid] = 0u; }
  __syncthreads();

  int sv[BIN_EPT], dv[BIN_EPT];
  #pragma unroll
  for (int i = 0; i < BIN_EPT; ++i) {
    const int e = e0 + i * 256 + tid;
    if (e < E) {
      sv[i] = srcp[e];
      dv[i] = dstp[e];
      atomicAdd(&bh[dv[i] >> BW_BITS], 1u);
    } else dv[i] = -1;
  }
  __syncthreads();

  if (tid < 128) {
    bbase[tid] = (tid < nbuck && bh[tid] > 0u)
                   ? atomicAdd(bcnt + (size_t)r * nbuck + tid, bh[tid]) : 0u;
  }
  __syncthreads();

  unsigned* bb = binBuf + (size_t)r * nbuck * BCAP;
  #pragma unroll
  for (int i = 0; i < BIN_EPT; ++i) {
    if (dv[i] >= 0) {
      const int b = dv[i] >> BW_BITS;
      const unsigned pos = bbase[b] + atomicAdd(&bcur[b], 1u);
      if (pos < (unsigned)BCAP)
        bb[(size_t)b * BCAP + pos] = (unsigned)sv[i] | ((unsigned)(dv[i] & (BWIDTH - 1)) << 17);
    }
  }
}

// tiny exclusive scan of per-bucket counts (per relation)
__global__ __launch_bounds__(64) void bscan_kernel(unsigned* bcnt, unsigned* bscan, int nbuck) {
  const int r = blockIdx.x;
  if (threadIdx.x == 0) {
    unsigned run = 0;
    for (int b = 0; b < nbuck; ++b) {
      unsigned c = bcnt[(size_t)r * nbuck + b];
      if (c > (unsigned)BCAP) c = BCAP;
      bcnt[(size_t)r * nbuck + b] = c;
      bscan[(size_t)r * nbuck + b] = run;
      run += c;
    }
  }
}

// Pass B: per (relation, bucket) block — count/scan/scatter in LDS, write
// perm + offsets + per-edge alpha fully coalesced. Runs AFTER proj.
struct CsrParams {
  const unsigned* binBuf;
  const unsigned* bcnt;
  const unsigned* bscan;
  unsigned* offsets;            // [9*(N+1)]
  unsigned* perm;               // [9*E]
  unsigned short* alf;          // [9*E*4] bf16 alpha per edge
  const float* sdot[9];
  const float* ddot[9];
  int N, E, nbuck;
};

__global__ __launch_bounds__(256) void csr_kernel(CsrParams cp) {
  const int r   = blockIdx.y;
  const int b   = blockIdx.x;
  const int tid = threadIdx.x;
  const int N = cp.N, E = cp.E, nbuck = cp.nbuck;
  const unsigned cnt  = cp.bcnt[(size_t)r * nbuck + b];
  const unsigned base = cp.bscan[(size_t)r * nbuck + b];
  const unsigned* buf = cp.binBuf + ((size_t)r * nbuck + b) * BCAP;
  unsigned* offr = cp.offsets + (size_t)r * (N + 1);
  unsigned* permr = cp.perm + (size_t)r * E;
  unsigned short* alfr = cp.alf + (size_t)r * E * 4;
  const float* sdr = cp.sdot[r];
  const float* ddr = cp.ddot[r];

  __shared__ unsigned S[BWIDTH];      // counts -> exclusive scan -> cursors
  __shared__ unsigned T[256];
  __shared__ unsigned permL[BCAP];    // 24 KB

  for (int i = tid; i < BWIDTH; i += 256) S[i] = 0u;
  __syncthreads();

  for (unsigned i = tid; i < cnt; i += 256) atomicAdd(&S[buf[i] >> 17], 1u);
  __syncthreads();

  // exclusive scan of S[0..1023]: 4 elems per thread + Hillis-Steele over 256
  const int b4 = tid * 4;
  unsigned loc0 = S[b4], loc1 = S[b4 + 1], loc2 = S[b4 + 2], loc3 = S[b4 + 3];
  unsigned s = loc0 + loc1 + loc2 + loc3;
  T[tid] = s;
  __syncthreads();
  for (int d = 1; d < 256; d <<= 1) {
    const unsigned v = T[tid];
    const unsigned a = (tid >= d) ? T[tid - d] : 0u;
    __syncthreads();
    T[tid] = v + a;
    __syncthreads();
  }
  unsigned run = T[tid] - s;   // exclusive across threads
  S[b4]     = run;  run += loc0;
  S[b4 + 1] = run;  run += loc1;
  S[b4 + 2] = run;  run += loc2;
  S[b4 + 3] = run;
  __syncthreads();

  // write global offsets for this bucket's dst range (coalesced)
  const int d0 = b * BWIDTH;
  for (int i = tid; i < BWIDTH; i += 256) {
    const int d = d0 + i;
    if (d < N) offr[d] = base + S[i];
  }
  if (b == 0 && tid == 0) offr[N] = (unsigned)E;
  __syncthreads();

  // scatter packed (src|dstLow) into LDS at CSR-local positions
  for (unsigned i = tid; i < cnt; i += 256) {
    const unsigned v = buf[i];
    const unsigned pos = atomicAdd(&S[v >> 17], 1u);
    permL[pos] = v;
  }
  __syncthreads();

  // stream out coalesced: perm (src only) + per-edge alpha (softmax once/edge)
  for (unsigned i = tid; i < cnt; i += 256) {
    const unsigned v = permL[i];
    const unsigned sv = v & 0x1FFFFu;
    const int dn = d0 + (int)(v >> 17);
    permr[base + i] = sv;

    const float4 sd = *(const float4*)(sdr + (size_t)sv * 4);
    const float4 dd = *(const float4*)(ddr + (size_t)dn * 4);
    float e0 = sd.x + dd.x, e1 = sd.y + dd.y, e2 = sd.z + dd.z, e3 = sd.w + dd.w;
    e0 = (e0 >= 0.f) ? e0 : 0.2f * e0;
    e1 = (e1 >= 0.f) ? e1 : 0.2f * e1;
    e2 = (e2 >= 0.f) ? e2 : 0.2f * e2;
    e3 = (e3 >= 0.f) ? e3 : 0.2f * e3;
    const float m = fmaxf(fmaxf(e0, e1), fmaxf(e2, e3));
    const float x0 = __expf(e0 - m);
    const float x1 = __expf(e1 - m);
    const float x2 = __expf(e2 - m);
    const float x3 = __expf(e3 - m);
    const float inv = 1.f / (x0 + x1 + x2 + x3);
    uint2 packed;
    packed.x = ((unsigned)f2bf_bits(x1 * inv) << 16) | f2bf_bits(x0 * inv);
    packed.y = ((unsigned)f2bf_bits(x3 * inv) << 16) | f2bf_bits(x2 * inv);
    *(uint2*)(alfr + (size_t)(base + i) * 4) = packed;
  }
}

// ---------------------------------------------------------------------------
// Aggregation: one 64-lane wave per (dst node, type); 4 edge-slots x 16 lanes.
// Alpha precomputed (bf16, CSR order) -> inner loop is load + 4 FMA.
// ---------------------------------------------------------------------------
struct AggParams {
  const unsigned* offsets[9];        // [N+1]
  const unsigned* perm[9];           // [E] src ids in dst-CSR order
  const unsigned short* alf[9];      // [E*4] bf16 alpha
  const unsigned short* wh[9];       // [N*64] bf16 bits
  float* outp[3];
  int N, E;
};

typedef __attribute__((ext_vector_type(4))) unsigned short us4;

__global__ __launch_bounds__(256) void agg_kernel(AggParams p) {
  const int t    = blockIdx.y;
  const int w    = threadIdx.x >> 6;
  const int lane = threadIdx.x & 63;
  const int n    = blockIdx.x * 4 + w;
  if (n >= p.N) return;
  const int slot = lane >> 4;       // edge slot 0..3
  const int l16  = lane & 15;       // col group (4 cols each)
  const int h    = l16 >> 2;        // head of cols 4*l16..4*l16+3

  float acc0 = 0.f, acc1 = 0.f, acc2 = 0.f, acc3 = 0.f;

  #pragma unroll
  for (int sj = 0; sj < 3; ++sj) {
    const int r = sj * 3 + t;
    const unsigned start = p.offsets[r][n];
    const unsigned end   = p.offsets[r][n + 1];
    const unsigned* pm = p.perm[r];
    const unsigned short* al = p.alf[r];
    const unsigned short* whr = p.wh[r];

    for (unsigned base = start; base < end; base += 4) {
      const unsigned pos  = base + slot;
      const unsigned posc = (pos < end) ? pos : (end - 1);
      const unsigned s = pm[posc];
      float a = bf2f(al[posc * 4 + h]);
      if (pos >= end) a = 0.f;
      const us4 wv = *(const us4*)(whr + (size_t)s * HD + l16 * 4);
      acc0 = fmaf(a, bf2f(wv.x), acc0);
      acc1 = fmaf(a, bf2f(wv.y), acc1);
      acc2 = fmaf(a, bf2f(wv.z), acc2);
      acc3 = fmaf(a, bf2f(wv.w), acc3);
    }
  }

  // reduce the 4 edge-slots (lanes differing in bits 4..5)
  acc0 += __shfl_xor(acc0, 16); acc1 += __shfl_xor(acc1, 16);
  acc2 += __shfl_xor(acc2, 16); acc3 += __shfl_xor(acc3, 16);
  acc0 += __shfl_xor(acc0, 32); acc1 += __shfl_xor(acc1, 32);
  acc2 += __shfl_xor(acc2, 32); acc3 += __shfl_xor(acc3, 32);

  if (slot == 0) {
    float4 v;
    v.x = fmaxf(acc0, 0.f); v.y = fmaxf(acc1, 0.f);
    v.z = fmaxf(acc2, 0.f); v.w = fmaxf(acc3, 0.f);
    *(float4*)(p.outp[t] + (size_t)n * HD + l16 * 4) = v;
  }
}

// ---------------------------------------------------------------------------
extern "C" void kernel_launch(void* const* d_in, const int* in_sizes, int n_in,
                              void* d_out, int out_size, void* d_ws, size_t ws_size,
                              hipStream_t stream) {
  const int N = in_sizes[0] / IN_F;     // 100000
  const int E = in_sizes[9 + 4];        // 400000
  const int nbuck = (N + BWIDTH - 1) >> BW_BITS;  // 98

  ProjParams pp; AggParams ap; EdgeLists el; CsrParams cp;
  pp.N = N; ap.N = N; ap.E = E; el.E = E; el.N = N;
  cp.N = N; cp.E = E; cp.nbuck = nbuck;

  for (int t = 0; t < 3; ++t) {
    pp.feat[t]  = (const float*)d_in[t * 3 + 0];
    pp.Wp[t][0] = (const float*)d_in[t * 3 + 1];
    pp.bp[t][0] = (const float*)d_in[t * 3 + 2];
    for (int j = 0; j < 3; ++j) {
      const int base = 9 + (t * 3 + j) * 6;
      pp.Wp[t][1 + j] = (const float*)d_in[base + 0];
      pp.bp[t][1 + j] = (const float*)d_in[base + 1];
    }
  }

  // workspace carve-up
  char* ws = (char*)d_ws;
  const size_t whBytes  = (size_t)N * HD * sizeof(__hip_bfloat16); // 12.8 MB
  const size_t dotBytes = (size_t)N * 4 * sizeof(float);           // 1.6 MB
  char* whBase   = ws;                                    // 9 * 12.8 MB
  char* sdotBase = whBase + 9 * whBytes;                  // 9 * 1.6 MB
  char* ddotBase = sdotBase + 9 * dotBytes;               // 9 * 1.6 MB
  unsigned* offsets = (unsigned*)(ddotBase + 9 * dotBytes);        // 9*(N+1)
  unsigned* bcnt    = offsets + (size_t)9 * (N + 1);               // 9*nbuck
  unsigned* bscan   = bcnt + (size_t)9 * ((nbuck + 63) & ~63);     // 9*nbuck
  unsigned* perm    = bscan + (size_t)9 * ((nbuck + 63) & ~63);    // 9*E
  unsigned short* alf = (unsigned short*)(perm + (size_t)9 * E);   // 9*E*4 bf16
  unsigned* binBuf  = (unsigned*)(alf + (size_t)9 * E * 4);        // 9*nbuck*BCAP

  cp.offsets = offsets; cp.perm = perm; cp.alf = alf;
  cp.binBuf = binBuf; cp.bcnt = bcnt; cp.bscan = bscan;

  for (int ri = 0; ri < 9; ++ri) {
    const int base = 9 + ri * 6;
    pp.asrc[ri] = (const float*)d_in[base + 2];
    pp.adst[ri] = (const float*)d_in[base + 3];
    pp.wh[ri]   = (__hip_bfloat16*)(whBase + (size_t)ri * whBytes);
    pp.sdot[ri] = (float*)(sdotBase + (size_t)ri * dotBytes);
    pp.ddot[ri] = (float*)(ddotBase + (size_t)ri * dotBytes);
    el.src[ri]  = (const int*)d_in[base + 4];
    el.dst[ri]  = (const int*)d_in[base + 5];
    cp.sdot[ri] = pp.sdot[ri];
    cp.ddot[ri] = pp.ddot[ri];
    ap.wh[ri]   = (const unsigned short*)pp.wh[ri];
    ap.alf[ri]  = alf + (size_t)ri * E * 4;
    ap.offsets[ri] = offsets + (size_t)ri * (N + 1);
    ap.perm[ri]    = perm + (size_t)ri * E;
  }
  for (int t = 0; t < 3; ++t) ap.outp[t] = (float*)d_out + (size_t)t * N * HD;

  // ---- binning (independent of proj) ----
  const int nbc = 9 * nbuck;
  zero_u32_kernel<<<dim3((nbc + 255) / 256), 256, 0, stream>>>(bcnt, nbc);
  bin_kernel<<<dim3((E + BIN_CHUNK - 1) / BIN_CHUNK, 9), 256, 0, stream>>>(el, bcnt, binBuf, nbuck);
  bscan_kernel<<<dim3(9), 64, 0, stream>>>(bcnt, bscan, nbuck);

  // ---- projections (produce wh, sdot, ddot) ----
  proj_kernel<<<dim3((N + BN - 1) / BN, 3), 256, 0, stream>>>(pp);

  // ---- CSR finalize + per-edge alpha (coalesced writes) ----
  csr_kernel<<<dim3(nbuck, 9), 256, 0, stream>>>(cp);

  // ---- dst-centric aggregation (alpha preloaded; one write per output elem) ----
  agg_kernel<<<dim3((N + 3) / 4, 3), 256, 0, stream>>>(ap);
}

// Round 7
// 609.550 us; speedup vs baseline: 1.1309x; 1.1309x over previous
//
#include <hip/hip_runtime.h>
#include <hip/hip_bf16.h>

// Problem constants (HeteroGATLayer): H=4 heads, D=16, IN=64, E=400000, N=100000
constexpr int IN_F = 64;   // input feature dim
constexpr int HD   = 64;   // H*D

// binned counting-sort parameters
constexpr int BW_BITS = 10;
constexpr int BWIDTH  = 1 << BW_BITS;   // 1024 dst nodes per bucket
constexpr int BCAP    = 6144;           // max edges per bucket (avg 4096)
constexpr int BIN_EPT = 16;             // edges per thread in bin pass
constexpr int BIN_CHUNK = 256 * BIN_EPT; // 4096 edges per block

// MFMA projection parameters
constexpr int PROJ_ROWS  = 128;  // rows per block
constexpr int LDS_STRIDE = 72;   // bf16 elems per LDS row (+8 pad: 2-way max)
constexpr int NJOBS      = 18;   // per type: 3 ddot + 3x(4 wh + 1 sdot)

typedef __attribute__((ext_vector_type(8))) short short8;   // 8 bf16 (4 VGPRs)
typedef __attribute__((ext_vector_type(4))) float floatx4;
typedef __attribute__((ext_vector_type(4))) unsigned short us4;

static __device__ __forceinline__ float bf2f(unsigned short u) {
  union { unsigned int i; float f; } c; c.i = ((unsigned int)u) << 16; return c.f;
}
static __device__ __forceinline__ unsigned short f2bf_bits(float f) {
  union { __hip_bfloat16 h; unsigned short u; } c; c.h = __float2bfloat16(f); return c.u;
}

// ---------------------------------------------------------------------------
// Prep kernel: build MFMA B-fragment packs (bf16, exact lane order) + bias
// packs for the 54 (type,job) pairs.
// job decode (per type t):
//   j<3          : ddot job, ri=j*3+t, B = (W_t · adst_ri) in cols 0..3
//   j>=3, jj=j-3 : p=jj/5, sub=jj%5, ri=t*3+p
//       sub<4    : wh job, B = W_ri[:, sub*16 .. sub*16+15]
//       sub==4   : sdot job, B = (W_ri · asrc_ri) in cols 0..3
// Bpack layout: [t][job][ktile(2)][lane(64)][8] bf16 ; bias: [t][job][16] f32
// MFMA B mapping: lane l holds B[k=kt*32+(l>>4)*8+jj][n=l&15]
// ---------------------------------------------------------------------------
struct PrepParams {
  const float* W[3][4];   // [t][p]: p0=self W_t, p1..3 = W_{t*3+(p-1)}
  const float* b[3][4];
  const float* asrc[9];
  const float* adst[9];
  unsigned short* Bpack;  // [3][18][2][64][8]
  float* biasPack;        // [3][18][16]
};

__global__ __launch_bounds__(64) void prep_kernel(PrepParams pp) {
  const int t = blockIdx.x / NJOBS;
  const int j = blockIdx.x % NJOBS;
  const int lane = threadIdx.x;
  const int q = lane >> 4, n = lane & 15;

  const float* W; const float* bv; const float* av = nullptr;
  int n0 = 0; bool dotjob;
  if (j < 3) {
    W = pp.W[t][0]; bv = pp.b[t][0]; av = pp.adst[j * 3 + t]; dotjob = true;
  } else {
    const int jj = j - 3, p = jj / 5, sub = jj % 5;
    W = pp.W[t][1 + p]; bv = pp.b[t][1 + p];
    if (sub < 4) { n0 = sub * 16; dotjob = false; }
    else { av = pp.asrc[t * 3 + p]; dotjob = true; }
  }

  unsigned short* outB = pp.Bpack + (size_t)(t * NJOBS + j) * 2 * 64 * 8;
  for (int kt = 0; kt < 2; ++kt) {
    for (int jj = 0; jj < 8; ++jj) {
      const int k = kt * 32 + q * 8 + jj;
      float v = 0.f;
      if (!dotjob) v = W[k * 64 + n0 + n];
      else if (n < 4) {
        for (int d = 0; d < 16; ++d) v += W[k * 64 + n * 16 + d] * av[n * 16 + d];
      }
      outB[(kt * 64 + lane) * 8 + jj] = f2bf_bits(v);
    }
  }
  if (lane < 16) {
    float v = 0.f;
    if (!dotjob) v = bv[n0 + lane];
    else if (lane < 4) {
      for (int d = 0; d < 16; ++d) v += bv[lane * 16 + d] * av[lane * 16 + d];
    }
    pp.biasPack[(t * NJOBS + j) * 16 + lane] = v;
  }
}

// ---------------------------------------------------------------------------
// MFMA projection kernel: block = 256 threads (4 waves) x 128 rows of type t.
// Stages feat tile as bf16 in LDS; each wave owns 32 rows (2 m-tiles of 16);
// loops 18 B-fragment jobs (software-pipelined loads), 2 MFMAs per m-tile.
// Wh_self is never materialized (ddot jobs are rank-4 projections).
// ---------------------------------------------------------------------------
struct ProjParams {
  const float* feat[3];
  const unsigned short* Bpack;
  const float* biasPack;
  unsigned short* wh[9];     // out: [N, 64] bf16 bits
  float* sdot[9];            // out: [N, 4]
  float* ddot[9];            // out: [N, 4]
  int N;
};

__global__ __launch_bounds__(256) void proj_kernel(ProjParams p) {
  const int t = blockIdx.y;
  const int n0blk = blockIdx.x * PROJ_ROWS;
  const int tid = threadIdx.x;
  const int N = p.N;

  __shared__ unsigned short featL[PROJ_ROWS * LDS_STRIDE];  // 18 KB

  // stage feat -> LDS bf16 (float4 coalesced loads, RNE cvt)
  {
    const float* feat = p.feat[t];
    #pragma unroll
    for (int c = 0; c < 8; ++c) {
      const int flat = c * 256 + tid;     // 0..2047 float4-slots
      const int row = flat >> 4;
      const int c4  = (flat & 15) << 2;
      const int gr = n0blk + row;
      float4 v = make_float4(0.f, 0.f, 0.f, 0.f);
      if (gr < N) v = *(const float4*)(feat + (size_t)gr * IN_F + c4);
      ushort4 o;
      o.x = f2bf_bits(v.x); o.y = f2bf_bits(v.y);
      o.z = f2bf_bits(v.z); o.w = f2bf_bits(v.w);
      *(ushort4*)(featL + row * LDS_STRIDE + c4) = o;
    }
  }
  __syncthreads();

  const int wave = tid >> 6;
  const int lane = tid & 63;
  const int q = lane >> 4, l15 = lane & 15;

  // A fragments: lane holds A[m=l15][k=q*8+jj] ; 2 m-tiles x 2 k-tiles
  short8 afrag[2][2];
  #pragma unroll
  for (int mt = 0; mt < 2; ++mt) {
    const int row = wave * 32 + mt * 16 + l15;
    #pragma unroll
    for (int kt = 0; kt < 2; ++kt) {
      afrag[mt][kt] = *(const short8*)(featL + row * LDS_STRIDE + kt * 32 + q * 8);
    }
  }

  const unsigned short* Bbase = p.Bpack + (size_t)t * NJOBS * 2 * 64 * 8;
  const float* biasBase = p.biasPack + (size_t)t * NJOBS * 16;

  // software-pipelined job loop: load j+1's fragments while computing j
  short8 b0 = *(const short8*)(Bbase + 0 * 512 + lane * 8);
  short8 b1 = *(const short8*)(Bbase + 1 * 512 + lane * 8);
  float bias = biasBase[l15];

  for (int j = 0; j < NJOBS; ++j) {
    short8 b0n, b1n; float biasn = 0.f;
    if (j + 1 < NJOBS) {
      b0n = *(const short8*)(Bbase + ((size_t)(j + 1) * 2 + 0) * 512 + lane * 8);
      b1n = *(const short8*)(Bbase + ((size_t)(j + 1) * 2 + 1) * 512 + lane * 8);
      biasn = biasBase[(j + 1) * 16 + l15];
    }

    #pragma unroll
    for (int mt = 0; mt < 2; ++mt) {
      floatx4 acc = {bias, bias, bias, bias};
      acc = __builtin_amdgcn_mfma_f32_16x16x32_bf16(afrag[mt][0], b0, acc, 0, 0, 0);
      acc = __builtin_amdgcn_mfma_f32_16x16x32_bf16(afrag[mt][1], b1, acc, 0, 0, 0);
      // C layout: row = q*4 + reg, col = l15
      const int rbase = n0blk + wave * 32 + mt * 16 + q * 4;
      if (j < 3) {                       // ddot job
        if (l15 < 4) {
          float* dp = p.ddot[j * 3 + t];
          #pragma unroll
          for (int r = 0; r < 4; ++r) {
            const int gr = rbase + r;
            if (gr < N) dp[(size_t)gr * 4 + l15] = acc[r];
          }
        }
      } else {
        const int jj = j - 3, pidx = jj / 5, sub = jj % 5, ri = t * 3 + pidx;
        if (sub < 4) {                   // wh job
          unsigned short* whp = p.wh[ri];
          #pragma unroll
          for (int r = 0; r < 4; ++r) {
            const int gr = rbase + r;
            if (gr < N) whp[(size_t)gr * HD + sub * 16 + l15] = f2bf_bits(acc[r]);
          }
        } else if (l15 < 4) {            // sdot job
          float* sp = p.sdot[ri];
          #pragma unroll
          for (int r = 0; r < 4; ++r) {
            const int gr = rbase + r;
            if (gr < N) sp[(size_t)gr * 4 + l15] = acc[r];
          }
        }
      }
    }
    b0 = b0n; b1 = b1n; bias = biasn;
  }
}

// ---------------------------------------------------------------------------
// CSR build, two-pass binned counting sort. Pass B also computes per-edge
// alpha (softmax over heads) once, written coalesced.
// ---------------------------------------------------------------------------
struct EdgeLists { const int* src[9]; const int* dst[9]; int E; int N; };

__global__ __launch_bounds__(256) void zero_u32_kernel(unsigned* p, int n) {
  const int i = blockIdx.x * 256 + threadIdx.x;
  if (i < n) p[i] = 0u;
}

// Pass A: bin edges into buckets of BWIDTH dst nodes; packed u32 per edge:
//   src (17 bits) | dstLow (10 bits) << 17
__global__ __launch_bounds__(256) void bin_kernel(EdgeLists el, unsigned* bcnt,
                                                  unsigned* binBuf, int nbuck) {
  const int r   = blockIdx.y;
  const int tid = threadIdx.x;
  const int e0  = blockIdx.x * BIN_CHUNK;
  const int E   = el.E;
  const int* srcp = el.src[r];
  const int* dstp = el.dst[r];

  __shared__ unsigned bh[128], bcur[128], bbase[128];
  if (tid < 128) { bh[tid] = 0u; bcur[tid] = 0u; }
  __syncthreads();

  int sv[BIN_EPT], dv[BIN_EPT];
  #pragma unroll
  for (int i = 0; i < BIN_EPT; ++i) {
    const int e = e0 + i * 256 + tid;
    if (e < E) {
      sv[i] = srcp[e];
      dv[i] = dstp[e];
      atomicAdd(&bh[dv[i] >> BW_BITS], 1u);
    } else dv[i] = -1;
  }
  __syncthreads();

  if (tid < 128) {
    bbase[tid] = (tid < nbuck && bh[tid] > 0u)
                   ? atomicAdd(bcnt + (size_t)r * nbuck + tid, bh[tid]) : 0u;
  }
  __syncthreads();

  unsigned* bb = binBuf + (size_t)r * nbuck * BCAP;
  #pragma unroll
  for (int i = 0; i < BIN_EPT; ++i) {
    if (dv[i] >= 0) {
      const int b = dv[i] >> BW_BITS;
      const unsigned pos = bbase[b] + atomicAdd(&bcur[b], 1u);
      if (pos < (unsigned)BCAP)
        bb[(size_t)b * BCAP + pos] = (unsigned)sv[i] | ((unsigned)(dv[i] & (BWIDTH - 1)) << 17);
    }
  }
}

// tiny exclusive scan of per-bucket counts (per relation)
__global__ __launch_bounds__(64) void bscan_kernel(unsigned* bcnt, unsigned* bscan, int nbuck) {
  const int r = blockIdx.x;
  if (threadIdx.x == 0) {
    unsigned run = 0;
    for (int b = 0; b < nbuck; ++b) {
      unsigned c = bcnt[(size_t)r * nbuck + b];
      if (c > (unsigned)BCAP) c = BCAP;
      bcnt[(size_t)r * nbuck + b] = c;
      bscan[(size_t)r * nbuck + b] = run;
      run += c;
    }
  }
}

// Pass B: per (relation, bucket) block — count/scan/scatter in LDS, write
// perm + offsets + per-edge alpha fully coalesced. Runs AFTER proj.
struct CsrParams {
  const unsigned* binBuf;
  const unsigned* bcnt;
  const unsigned* bscan;
  unsigned* offsets;            // [9*(N+1)]
  unsigned* perm;               // [9*E]
  unsigned short* alf;          // [9*E*4] bf16 alpha per edge
  const float* sdot[9];
  const float* ddot[9];
  int N, E, nbuck;
};

__global__ __launch_bounds__(256) void csr_kernel(CsrParams cp) {
  const int r   = blockIdx.y;
  const int b   = blockIdx.x;
  const int tid = threadIdx.x;
  const int N = cp.N, E = cp.E, nbuck = cp.nbuck;
  const unsigned cnt  = cp.bcnt[(size_t)r * nbuck + b];
  const unsigned base = cp.bscan[(size_t)r * nbuck + b];
  const unsigned* buf = cp.binBuf + ((size_t)r * nbuck + b) * BCAP;
  unsigned* offr = cp.offsets + (size_t)r * (N + 1);
  unsigned* permr = cp.perm + (size_t)r * E;
  unsigned short* alfr = cp.alf + (size_t)r * E * 4;
  const float* sdr = cp.sdot[r];
  const float* ddr = cp.ddot[r];

  __shared__ unsigned S[BWIDTH];
  __shared__ unsigned T[256];
  __shared__ unsigned permL[BCAP];    // 24 KB

  for (int i = tid; i < BWIDTH; i += 256) S[i] = 0u;
  __syncthreads();

  for (unsigned i = tid; i < cnt; i += 256) atomicAdd(&S[buf[i] >> 17], 1u);
  __syncthreads();

  // exclusive scan of S[0..1023]
  const int b4 = tid * 4;
  unsigned loc0 = S[b4], loc1 = S[b4 + 1], loc2 = S[b4 + 2], loc3 = S[b4 + 3];
  unsigned s = loc0 + loc1 + loc2 + loc3;
  T[tid] = s;
  __syncthreads();
  for (int d = 1; d < 256; d <<= 1) {
    const unsigned v = T[tid];
    const unsigned a = (tid >= d) ? T[tid - d] : 0u;
    __syncthreads();
    T[tid] = v + a;
    __syncthreads();
  }
  unsigned run = T[tid] - s;
  S[b4]     = run;  run += loc0;
  S[b4 + 1] = run;  run += loc1;
  S[b4 + 2] = run;  run += loc2;
  S[b4 + 3] = run;
  __syncthreads();

  const int d0 = b * BWIDTH;
  for (int i = tid; i < BWIDTH; i += 256) {
    const int d = d0 + i;
    if (d < N) offr[d] = base + S[i];
  }
  if (b == 0 && tid == 0) offr[N] = (unsigned)E;
  __syncthreads();

  for (unsigned i = tid; i < cnt; i += 256) {
    const unsigned v = buf[i];
    const unsigned pos = atomicAdd(&S[v >> 17], 1u);
    permL[pos] = v;
  }
  __syncthreads();

  for (unsigned i = tid; i < cnt; i += 256) {
    const unsigned v = permL[i];
    const unsigned sv = v & 0x1FFFFu;
    const int dn = d0 + (int)(v >> 17);
    permr[base + i] = sv;

    const float4 sd = *(const float4*)(sdr + (size_t)sv * 4);
    const float4 dd = *(const float4*)(ddr + (size_t)dn * 4);
    float e0 = sd.x + dd.x, e1 = sd.y + dd.y, e2 = sd.z + dd.z, e3 = sd.w + dd.w;
    e0 = (e0 >= 0.f) ? e0 : 0.2f * e0;
    e1 = (e1 >= 0.f) ? e1 : 0.2f * e1;
    e2 = (e2 >= 0.f) ? e2 : 0.2f * e2;
    e3 = (e3 >= 0.f) ? e3 : 0.2f * e3;
    const float m = fmaxf(fmaxf(e0, e1), fmaxf(e2, e3));
    const float x0 = __expf(e0 - m);
    const float x1 = __expf(e1 - m);
    const float x2 = __expf(e2 - m);
    const float x3 = __expf(e3 - m);
    const float inv = 1.f / (x0 + x1 + x2 + x3);
    uint2 packed;
    packed.x = ((unsigned)f2bf_bits(x1 * inv) << 16) | f2bf_bits(x0 * inv);
    packed.y = ((unsigned)f2bf_bits(x3 * inv) << 16) | f2bf_bits(x2 * inv);
    *(uint2*)(alfr + (size_t)(base + i) * 4) = packed;
  }
}

// ---------------------------------------------------------------------------
// Aggregation: one 64-lane wave per (dst node, type); 4 edge-slots x 16 lanes.
// Alpha precomputed (bf16, CSR order) -> inner loop is load + 4 FMA.
// ---------------------------------------------------------------------------
struct AggParams {
  const unsigned* offsets[9];        // [N+1]
  const unsigned* perm[9];           // [E] src ids in dst-CSR order
  const unsigned short* alf[9];      // [E*4] bf16 alpha
  const unsigned short* wh[9];       // [N*64] bf16 bits
  float* outp[3];
  int N, E;
};

__global__ __launch_bounds__(256) void agg_kernel(AggParams p) {
  const int t    = blockIdx.y;
  const int w    = threadIdx.x >> 6;
  const int lane = threadIdx.x & 63;
  const int n    = blockIdx.x * 4 + w;
  if (n >= p.N) return;
  const int slot = lane >> 4;       // edge slot 0..3
  const int l16  = lane & 15;       // col group (4 cols each)
  const int h    = l16 >> 2;        // head of cols 4*l16..4*l16+3

  float acc0 = 0.f, acc1 = 0.f, acc2 = 0.f, acc3 = 0.f;

  #pragma unroll
  for (int sj = 0; sj < 3; ++sj) {
    const int r = sj * 3 + t;
    const unsigned start = p.offsets[r][n];
    const unsigned end   = p.offsets[r][n + 1];
    const unsigned* pm = p.perm[r];
    const unsigned short* al = p.alf[r];
    const unsigned short* whr = p.wh[r];

    for (unsigned base = start; base < end; base += 4) {
      const unsigned pos  = base + slot;
      const unsigned posc = (pos < end) ? pos : (end - 1);
      const unsigned s = pm[posc];
      float a = bf2f(al[posc * 4 + h]);
      if (pos >= end) a = 0.f;
      const us4 wv = *(const us4*)(whr + (size_t)s * HD + l16 * 4);
      acc0 = fmaf(a, bf2f(wv.x), acc0);
      acc1 = fmaf(a, bf2f(wv.y), acc1);
      acc2 = fmaf(a, bf2f(wv.z), acc2);
      acc3 = fmaf(a, bf2f(wv.w), acc3);
    }
  }

  acc0 += __shfl_xor(acc0, 16); acc1 += __shfl_xor(acc1, 16);
  acc2 += __shfl_xor(acc2, 16); acc3 += __shfl_xor(acc3, 16);
  acc0 += __shfl_xor(acc0, 32); acc1 += __shfl_xor(acc1, 32);
  acc2 += __shfl_xor(acc2, 32); acc3 += __shfl_xor(acc3, 32);

  if (slot == 0) {
    float4 v;
    v.x = fmaxf(acc0, 0.f); v.y = fmaxf(acc1, 0.f);
    v.z = fmaxf(acc2, 0.f); v.w = fmaxf(acc3, 0.f);
    *(float4*)(p.outp[t] + (size_t)n * HD + l16 * 4) = v;
  }
}

// ---------------------------------------------------------------------------
extern "C" void kernel_launch(void* const* d_in, const int* in_sizes, int n_in,
                              void* d_out, int out_size, void* d_ws, size_t ws_size,
                              hipStream_t stream) {
  const int N = in_sizes[0] / IN_F;     // 100000
  const int E = in_sizes[9 + 4];        // 400000
  const int nbuck = (N + BWIDTH - 1) >> BW_BITS;  // 98

  ProjParams pp; AggParams ap; EdgeLists el; CsrParams cp; PrepParams qq;
  pp.N = N; ap.N = N; ap.E = E; el.E = E; el.N = N;
  cp.N = N; cp.E = E; cp.nbuck = nbuck;

  for (int t = 0; t < 3; ++t) {
    pp.feat[t] = (const float*)d_in[t * 3 + 0];
    qq.W[t][0] = (const float*)d_in[t * 3 + 1];
    qq.b[t][0] = (const float*)d_in[t * 3 + 2];
    for (int j = 0; j < 3; ++j) {
      const int base = 9 + (t * 3 + j) * 6;
      qq.W[t][1 + j] = (const float*)d_in[base + 0];
      qq.b[t][1 + j] = (const float*)d_in[base + 1];
    }
  }

  // workspace carve-up
  char* ws = (char*)d_ws;
  const size_t whBytes  = (size_t)N * HD * sizeof(__hip_bfloat16); // 12.8 MB
  const size_t dotBytes = (size_t)N * 4 * sizeof(float);           // 1.6 MB
  char* whBase   = ws;                                    // 9 * 12.8 MB
  char* sdotBase = whBase + 9 * whBytes;                  // 9 * 1.6 MB
  char* ddotBase = sdotBase + 9 * dotBytes;               // 9 * 1.6 MB
  unsigned* offsets = (unsigned*)(ddotBase + 9 * dotBytes);        // 9*(N+1)
  unsigned* bcnt    = offsets + (size_t)9 * (N + 1);               // 9*nbuck
  unsigned* bscan   = bcnt + (size_t)9 * ((nbuck + 63) & ~63);     // 9*nbuck
  unsigned* perm    = bscan + (size_t)9 * ((nbuck + 63) & ~63);    // 9*E
  unsigned short* alf = (unsigned short*)(perm + (size_t)9 * E);   // 9*E*4 bf16
  unsigned* binBuf  = (unsigned*)(alf + (size_t)9 * E * 4);        // 9*nbuck*BCAP
  unsigned short* Bpack = (unsigned short*)(binBuf + (size_t)9 * nbuck * BCAP);
  float* biasPack = (float*)(Bpack + (size_t)3 * NJOBS * 2 * 64 * 8);

  cp.offsets = offsets; cp.perm = perm; cp.alf = alf;
  cp.binBuf = binBuf; cp.bcnt = bcnt; cp.bscan = bscan;
  qq.Bpack = Bpack; qq.biasPack = biasPack;
  pp.Bpack = Bpack; pp.biasPack = biasPack;

  for (int ri = 0; ri < 9; ++ri) {
    const int base = 9 + ri * 6;
    qq.asrc[ri] = (const float*)d_in[base + 2];
    qq.adst[ri] = (const float*)d_in[base + 3];
    pp.wh[ri]   = (unsigned short*)(whBase + (size_t)ri * whBytes);
    pp.sdot[ri] = (float*)(sdotBase + (size_t)ri * dotBytes);
    pp.ddot[ri] = (float*)(ddotBase + (size_t)ri * dotBytes);
    el.src[ri]  = (const int*)d_in[base + 4];
    el.dst[ri]  = (const int*)d_in[base + 5];
    cp.sdot[ri] = pp.sdot[ri];
    cp.ddot[ri] = pp.ddot[ri];
    ap.wh[ri]   = pp.wh[ri];
    ap.alf[ri]  = alf + (size_t)ri * E * 4;
    ap.offsets[ri] = offsets + (size_t)ri * (N + 1);
    ap.perm[ri]    = perm + (size_t)ri * E;
  }
  for (int t = 0; t < 3; ++t) ap.outp[t] = (float*)d_out + (size_t)t * N * HD;

  // ---- prep B-fragment packs (independent) ----
  prep_kernel<<<dim3(3 * NJOBS), 64, 0, stream>>>(qq);

  // ---- binning (independent of proj) ----
  const int nbc = 9 * nbuck;
  zero_u32_kernel<<<dim3((nbc + 255) / 256), 256, 0, stream>>>(bcnt, nbc);
  bin_kernel<<<dim3((E + BIN_CHUNK - 1) / BIN_CHUNK, 9), 256, 0, stream>>>(el, bcnt, binBuf, nbuck);
  bscan_kernel<<<dim3(9), 64, 0, stream>>>(bcnt, bscan, nbuck);

  // ---- MFMA projections (produce wh, sdot, ddot) ----
  proj_kernel<<<dim3((N + PROJ_ROWS - 1) / PROJ_ROWS, 3), 256, 0, stream>>>(pp);

  // ---- CSR finalize + per-edge alpha (coalesced writes) ----
  csr_kernel<<<dim3(nbuck, 9), 256, 0, stream>>>(cp);

  // ---- dst-centric aggregation (one write per output elem) ----
  agg_kernel<<<dim3((N + 3) / 4, 3), 256, 0, stream>>>(ap);
}